// Round 1
// baseline (345.451 us; speedup 1.0000x reference)
//
#include <hip/hip_runtime.h>

// SoftDepthShader: softmax depth blend over K=50 rasterizer slots per pixel.
// N=8, H=256, W=256, K=50 -> 524288 pixels, 26,214,400 elements per array.
// Memory-bound: ~317 MB HBM traffic, floor ~50 us at 6.3 TB/s.

constexpr int K       = 50;
constexpr int KP      = 51;            // LDS pixel stride; 51 coprime w/ 32 banks -> conflict-free
constexpr int PPB     = 128;           // pixels per block
constexpr int THREADS = 128;
constexpr int EPB     = PPB * K;       // 6400 elements per block per array
constexpr int F2_PER_THREAD = EPB / 2 / THREADS;  // 25 float2 loads per thread

constexpr float SIGMA     = 1e-4f;
constexpr float INV_SIGMA = 1.0f / SIGMA;
constexpr float GAMMA     = 1e-4f;
constexpr float INVG      = 1.0f / GAMMA;
constexpr float ZFAR      = 100.0f;
constexpr float ZRANGE    = 99.0f;          // zfar - znear
constexpr float INV_ZRANGE= 1.0f / 99.0f;
constexpr float EPS       = 1e-10f;

__global__ __launch_bounds__(THREADS) void soft_depth_kernel(
    const float* __restrict__ zbuf,
    const float* __restrict__ dists,
    const int*   __restrict__ p2f,
    float*       __restrict__ out)
{
    // 52.2 KB LDS: z_inv and prob per element, pixel stride 51 floats
    __shared__ float s_z[PPB * KP];
    __shared__ float s_p[PPB * KP];

    const int t = threadIdx.x;
    const size_t base2 = (size_t)blockIdx.x * (EPB / 2);  // float2-unit base
    const float2* __restrict__ z2 = (const float2*)zbuf  + base2;
    const float2* __restrict__ d2 = (const float2*)dists + base2;
    const int2*   __restrict__ f2 = (const int2*)p2f     + base2;

    // ---- Stage: coalesced global -> elementwise transform -> LDS (transposed) ----
    // K=50 is even, so each float2 (element pair 2j, 2j+1) lies within one pixel.
    #pragma unroll 5
    for (int i = 0; i < F2_PER_THREAD; ++i) {
        const int idx = t + i * THREADS;        // float2 index within tile
        const float2 z = z2[idx];
        const float2 d = d2[idx];
        const int2   f = f2[idx];
        const int e0 = idx * 2;                 // element index within tile (even)
        const int p  = (int)((unsigned)e0 / (unsigned)K);
        const int k  = e0 - p * K;

        const bool m0 = (f.x >= 0);
        const bool m1 = (f.y >= 0);
        const float zi0 = m0 ? (ZFAR - z.x) * INV_ZRANGE : 0.0f;
        const float zi1 = m1 ? (ZFAR - z.y) * INV_ZRANGE : 0.0f;
        // prob = sigmoid(-d/sigma) = 1/(1+exp(d/sigma)); exact 0 where masked
        const float pr0 = m0 ? 1.0f / (1.0f + __expf(d.x * INV_SIGMA)) : 0.0f;
        const float pr1 = m1 ? 1.0f / (1.0f + __expf(d.y * INV_SIGMA)) : 0.0f;

        const int a = p * KP + k;
        s_z[a]     = zi0;
        s_z[a + 1] = zi1;
        s_p[a]     = pr0;
        s_p[a + 1] = pr1;
    }
    __syncthreads();

    // ---- Reduce: one thread per pixel, online softmax over K=50 ----
    // LDS read addr = t*51 + k : stride 51 across lanes -> 2 lanes/bank (free).
    float m  = EPS;   // matches reference z_inv_max = max(max_k z_inv, EPS)
    float S1 = 0.0f;  // sum of weights
    float S2 = 0.0f;  // sum of weights * zbuf
    const int base = t * KP;
    #pragma unroll 10
    for (int k = 0; k < K; ++k) {
        const float z  = s_z[base + k];
        const float pr = s_p[base + k];
        const float mn = fmaxf(m, z);
        const float sc = __expf((m - mn) * INVG);   // rescale old sums (==1 if max unchanged)
        const float e  = __expf((z - mn) * INVG);
        const float w  = pr * e;
        // reconstruct zbuf from z_inv; where masked w==0 so the bogus value is harmless
        const float zb = ZFAR - z * ZRANGE;
        S1 = S1 * sc + w;
        S2 = S2 * sc + w * zb;
        m  = mn;
    }
    const float delta = fmaxf(__expf((EPS - m) * INVG), EPS);
    out[(size_t)blockIdx.x * PPB + t] = (S2 + delta) / (S1 + delta);  // BG_BLUE = 1
}

extern "C" void kernel_launch(void* const* d_in, const int* in_sizes, int n_in,
                              void* d_out, int out_size, void* d_ws, size_t ws_size,
                              hipStream_t stream) {
    const float* zbuf  = (const float*)d_in[0];
    const float* dists = (const float*)d_in[1];
    const int*   p2f   = (const int*)d_in[2];
    float* out = (float*)d_out;

    const int total_elems = in_sizes[0];        // 26,214,400
    const int blocks = total_elems / EPB;       // 4096 (exact)

    soft_depth_kernel<<<dim3(blocks), dim3(THREADS), 0, stream>>>(
        zbuf, dists, p2f, out);
}